// Round 3
// baseline (96.422 us; speedup 1.0000x reference)
//
#include <hip/hip_runtime.h>

#define NPTS 96
#define HID  64
#define RANK 32

typedef float f2   __attribute__((ext_vector_type(2)));
typedef float f4   __attribute__((ext_vector_type(4)));
typedef float sf16 __attribute__((ext_vector_type(16)));

// ws layout (floats):
//   plain[axis][f][n] : axis*RANK*NPTS + f*NPTS + n
//   trans[axis][n][f] : TRANS_OFF + (axis*NPTS+n)*RANK + f
//   fxdup[x][2f(+1)]  : DUP_OFF + x*2*RANK + 2*f (+1)   (fx duplicated pairwise)
#define TRANS_OFF (4 * RANK * NPTS)
#define DUP_OFF   (8 * RANK * NPTS)

// -------- Kernel 1: the 4 tiny MLPs -> factor matrices in ws --------
__global__ __launch_bounds__(64) void spinn_mlp(
    const float* __restrict__ t, const float* __restrict__ x,
    const float* __restrict__ y, const float* __restrict__ z,
    const float* __restrict__ W1, const float* __restrict__ b1,
    const float* __restrict__ W2, const float* __restrict__ b2,
    const float* __restrict__ W3, const float* __restrict__ b3,
    float* __restrict__ ws)
{
    const int n    = blockIdx.x;   // point 0..95
    const int axis = blockIdx.y;   // 0..3
    const int j    = threadIdx.x;  // 0..63

    const float* coords[4] = { t, x, y, z };
    const float c = coords[axis][n];

    __shared__ float h1[HID];
    __shared__ float h2[HID];

    h1[j] = tanhf(fmaf(c, W1[axis * HID + j], b1[axis * HID + j]));
    __syncthreads();

    float a = b2[axis * HID + j];
    #pragma unroll
    for (int k = 0; k < HID; ++k)
        a = fmaf(h1[k], W2[(axis * HID + k) * HID + j], a);
    h2[j] = tanhf(a);
    __syncthreads();

    if (j < RANK) {
        float o = b3[axis * RANK + j];
        #pragma unroll
        for (int k = 0; k < HID; ++k)
            o = fmaf(h2[k], W3[(axis * HID + k) * RANK + j], o);
        ws[axis * RANK * NPTS + j * NPTS + n]              = o; // plain [axis][f][n]
        ws[TRANS_OFF + (axis * NPTS + n) * RANK + j]       = o; // trans [axis][n][f]
        if (axis == 1) {                                        // fx pair-duplicated
            ws[DUP_OFF + n * (2 * RANK) + 2 * j]     = o;
            ws[DUP_OFF + n * (2 * RANK) + 2 * j + 1] = o;
        }
    }
}

// -------- Kernel 2: rank-32 CP reconstruction, 96^4 fp32 output --------
__global__ __launch_bounds__(192) void spinn_outer(
    const float* __restrict__ ws, float* __restrict__ out)
{
    const int tt  = blockIdx.x;        // t: 0..95
    const int yb  = blockIdx.y;        // y block: 0..11
    const int xh  = blockIdx.z;        // x half: 0..1
    const int tid = threadIdx.x;       // 0..191
    const int yq  = tid / 24;          // 0..7
    const int z4  = tid % 24;          // 0..23
    const int yy  = yb * 8 + yq;
    const int z0  = z4 * 4;

    const float* ftT = ws + TRANS_OFF + (0 * NPTS + tt) * RANK;  // 32 contiguous
    const float* fyT = ws + TRANS_OFF + (2 * NPTS + yy) * RANK;  // 32 contiguous
    const float* fzP = ws + 3 * RANK * NPTS;                      // fz[f][n]

    // q[f] = ft[f]*fy[f]*fz[f][z0..z0+3], register-resident (128 VGPRs)
    f2 q0[RANK], q1[RANK];
    #pragma unroll
    for (int f = 0; f < RANK; ++f) {
        const float g = ftT[f] * fyT[f];
        const float* fzf = fzP + f * NPTS + z0;
        f2 a = { fzf[0], fzf[1] };
        f2 b = { fzf[2], fzf[3] };
        q0[f] = a * g;
        q1[f] = b * g;
    }

    const int x0 = xh * 48;
    const float* dup = ws + DUP_OFF;
    float* outp = out + (size_t)tt * NPTS * NPTS * NPTS
                      + (size_t)x0 * NPTS * NPTS
                      + (size_t)yy * NPTS + z0;

    for (int xs = 0; xs < 48; ++xs) {
        // 64 floats (32 duplicated pairs) -> 64 SGPRs; wait inside asm block
        const float* fxa = dup + (size_t)(x0 + xs) * (2 * RANK);  // uniform addr
        sf16 d0, d1, d2, d3;
        asm volatile(
            "s_load_dwordx16 %0, %4, 0x0\n\t"
            "s_load_dwordx16 %1, %4, 0x40\n\t"
            "s_load_dwordx16 %2, %4, 0x80\n\t"
            "s_load_dwordx16 %3, %4, 0xC0\n\t"
            "s_waitcnt lgkmcnt(0)"
            : "=s"(d0), "=s"(d1), "=s"(d2), "=s"(d3)
            : "s"(fxa));

        f2 acc0a = {0.f, 0.f}, acc0b = {0.f, 0.f};
        f2 acc1a = {0.f, 0.f}, acc1b = {0.f, 0.f};

        // s2 = aligned SGPR pair (s,s); v_pk_fma_f32 takes it as the one scalar src
        #define STEP(vec, k, f0)                                            \
        {                                                                   \
            f2 s2 = __builtin_shufflevector(vec, vec, 2*(k), 2*(k)+1);      \
            if ((k) & 1) {                                                  \
                asm("v_pk_fma_f32 %0, %2, %3, %0\n\t"                       \
                    "v_pk_fma_f32 %1, %2, %4, %1"                           \
                    : "+v"(acc0b), "+v"(acc1b)                              \
                    : "s"(s2), "v"(q0[f0]), "v"(q1[f0]));                   \
            } else {                                                        \
                asm("v_pk_fma_f32 %0, %2, %3, %0\n\t"                       \
                    "v_pk_fma_f32 %1, %2, %4, %1"                           \
                    : "+v"(acc0a), "+v"(acc1a)                              \
                    : "s"(s2), "v"(q0[f0]), "v"(q1[f0]));                   \
            }                                                               \
        }
        #define GRP8(vec, f0)                                               \
            STEP(vec, 0, (f0)+0) STEP(vec, 1, (f0)+1)                       \
            STEP(vec, 2, (f0)+2) STEP(vec, 3, (f0)+3)                       \
            STEP(vec, 4, (f0)+4) STEP(vec, 5, (f0)+5)                       \
            STEP(vec, 6, (f0)+6) STEP(vec, 7, (f0)+7)

        GRP8(d0, 0) GRP8(d1, 8) GRP8(d2, 16) GRP8(d3, 24)
        #undef GRP8
        #undef STEP

        f2 r0 = acc0a + acc0b;
        f2 r1 = acc1a + acc1b;
        f4 res = { r0.x, r0.y, r1.x, r1.y };
        __builtin_nontemporal_store(res, (f4*)outp);
        outp += NPTS * NPTS;
    }
}

extern "C" void kernel_launch(void* const* d_in, const int* in_sizes, int n_in,
                              void* d_out, int out_size, void* d_ws, size_t ws_size,
                              hipStream_t stream)
{
    const float* t  = (const float*)d_in[0];
    const float* x  = (const float*)d_in[1];
    const float* y  = (const float*)d_in[2];
    const float* z  = (const float*)d_in[3];
    const float* W1 = (const float*)d_in[4];
    const float* b1 = (const float*)d_in[5];
    const float* W2 = (const float*)d_in[6];
    const float* b2 = (const float*)d_in[7];
    const float* W3 = (const float*)d_in[8];
    const float* b3 = (const float*)d_in[9];

    float* ws  = (float*)d_ws;
    float* out = (float*)d_out;

    spinn_mlp<<<dim3(NPTS, 4), 64, 0, stream>>>(t, x, y, z, W1, b1, W2, b2, W3, b3, ws);
    spinn_outer<<<dim3(NPTS, 12, 2), 192, 0, stream>>>(ws, out);
}